// Round 15
// baseline (478.422 us; speedup 1.0000x reference)
//
#include <hip/hip_runtime.h>
#include <math.h>

#define H 128
#define IN 2048
#define PROJ 64
#define BT 32768      // B*T rows of x
#define T_STEPS 512
#define BATCH 64
#define BM 128
#define BKA 64

using f32x4  = __attribute__((ext_vector_type(4))) float;
using bfrag  = __attribute__((ext_vector_type(8))) short;   // 8 bf16
using h2_t   = __attribute__((ext_vector_type(2))) _Float16;

// v_cvt_pk_bf16_f32: d.lo = bf16(lo), d.hi = bf16(hi)  (RNE)
__device__ __forceinline__ unsigned cvtpk(float lo, float hi) {
  unsigned r;
  asm("v_cvt_pk_bf16_f32 %0, %1, %2" : "=v"(r) : "v"(lo), "v"(hi));
  return r;
}

// ---------------------------------------------------------------------------
// Kernel A: xp1[BT][H] = x[BT][IN] @ W_ih1^T + (b_ih1+b_hh1), bf16 MFMA.
// UNCHANGED (~60 us, near HBM floor).
// ---------------------------------------------------------------------------
__global__ __launch_bounds__(512) void xp1_gemm(
    const float* __restrict__ x, const float* __restrict__ W,
    const float* __restrict__ b1, const float* __restrict__ b2,
    float* __restrict__ xp1) {
  __shared__ __align__(16) char As[2][BM * BKA * 2];   // 2 x 16 KB
  __shared__ __align__(16) char Bs[2][H * BKA * 2];    // 2 x 16 KB
  const int t  = threadIdx.x;
  const int m0 = blockIdx.x * BM;
  const int wv = t >> 6, l = t & 63;
  const int wm = wv >> 2;
  const int wn = wv & 3;
  const int lr = l & 15;
  const int lq = l >> 4;

  const float* xg[4];
  const float* wg[4];
  int so[4];
#pragma unroll
  for (int i = 0; i < 4; ++i) {
    int c = t + 512 * i, r = c >> 4, k4 = c & 15;
    xg[i] = x + (size_t)(m0 + r) * IN + k4 * 4;
    wg[i] = W + (size_t)r * IN + k4 * 4;
    so[i] = (r * 128 + k4 * 8) ^ ((r & 7) << 4);
  }
  int ao[2][4], bo[2][2];
#pragma unroll
  for (int kf = 0; kf < 2; ++kf) {
#pragma unroll
    for (int mf = 0; mf < 4; ++mf) {
      int r = wm * 64 + mf * 16 + lr;
      ao[kf][mf] = (r * 128 + kf * 64 + lq * 16) ^ ((r & 7) << 4);
    }
#pragma unroll
    for (int nf = 0; nf < 2; ++nf) {
      int r = wn * 32 + nf * 16 + lr;
      bo[kf][nf] = (r * 128 + kf * 64 + lq * 16) ^ ((r & 7) << 4);
    }
  }

  f32x4 acc[4][2];
#pragma unroll
  for (int mf = 0; mf < 4; ++mf)
#pragma unroll
    for (int nf = 0; nf < 2; ++nf)
#pragma unroll
      for (int j = 0; j < 4; ++j) acc[mf][nf][j] = 0.f;

  float4 xr[4], wr[4];
#pragma unroll
  for (int i = 0; i < 4; ++i) {
    xr[i] = *(const float4*)&xg[i][0];
    wr[i] = *(const float4*)&wg[i][0];
  }
#pragma unroll
  for (int i = 0; i < 4; ++i) {
    uint2 ux; ux.x = cvtpk(xr[i].x, xr[i].y); ux.y = cvtpk(xr[i].z, xr[i].w);
    *(uint2*)(As[0] + so[i]) = ux;
    uint2 uw; uw.x = cvtpk(wr[i].x, wr[i].y); uw.y = cvtpk(wr[i].z, wr[i].w);
    *(uint2*)(Bs[0] + so[i]) = uw;
  }
  __syncthreads();

  for (int tc = 0; tc < 32; ++tc) {
    const int kc = (tc + 1) * BKA;
    if (tc < 31) {
#pragma unroll
      for (int i = 0; i < 4; ++i) {
        xr[i] = *(const float4*)&xg[i][kc];
        wr[i] = *(const float4*)&wg[i][kc];
      }
    }
    const char* Ab = As[tc & 1];
    const char* Bb = Bs[tc & 1];
#pragma unroll
    for (int kf = 0; kf < 2; ++kf) {
      bfrag af[4], bf[2];
#pragma unroll
      for (int mf = 0; mf < 4; ++mf) af[mf] = *(const bfrag*)(Ab + ao[kf][mf]);
#pragma unroll
      for (int nf = 0; nf < 2; ++nf) bf[nf] = *(const bfrag*)(Bb + bo[kf][nf]);
#pragma unroll
      for (int mf = 0; mf < 4; ++mf)
#pragma unroll
        for (int nf = 0; nf < 2; ++nf)
          acc[mf][nf] = __builtin_amdgcn_mfma_f32_16x16x32_bf16(
              af[mf], bf[nf], acc[mf][nf], 0, 0, 0);
    }
    if (tc < 31) {
      char* Aw = As[(tc + 1) & 1];
      char* Bw = Bs[(tc + 1) & 1];
#pragma unroll
      for (int i = 0; i < 4; ++i) {
        uint2 ux; ux.x = cvtpk(xr[i].x, xr[i].y); ux.y = cvtpk(xr[i].z, xr[i].w);
        *(uint2*)(Aw + so[i]) = ux;
        uint2 uw; uw.x = cvtpk(wr[i].x, wr[i].y); uw.y = cvtpk(wr[i].z, wr[i].w);
        *(uint2*)(Bw + so[i]) = uw;
      }
    }
    __syncthreads();
  }

  // epilogue: C/D layout col = lane&15, row = (lane>>4)*4 + j   [m89]
#pragma unroll
  for (int nf = 0; nf < 2; ++nf) {
    int n = wn * 32 + nf * 16 + lr;
    float bias = b1[n] + b2[n];
#pragma unroll
    for (int mf = 0; mf < 4; ++mf) {
      int mr = m0 + wm * 64 + mf * 16 + lq * 4;
#pragma unroll
      for (int j = 0; j < 4; ++j)
        xp1[(size_t)(mr + j) * H + n] = acc[mf][nf][j] + bias;
    }
  }
}

// ---------------------------------------------------------------------------
// Kernel B: fused 2-layer tanh RNN — R12 structure, datapath = SCALAR
// v_fma_f32 (the only HW-verified 2-cyc full-rate op, m07). A/B against the
// dot2 path: R8/R12/R14 all have 384 dot2 wave-instrs/CU-step and all land
// 337-376 us -> time tracks total dot-instr count at ~10 cyc/instr (slow
// shared pipe). Here: h stays f16 in LDS (R12's conflict-free layout),
// expanded via v_cvt_f32_f16 (32/thread); weights raw f32 asm-resident
// float4s; 96 fma + 32 cvt per thread per step at full rate.
// Everything else identical to R12 (skew, raw lgkm barrier, parity unroll,
// 2-deep xp prefetch, row-pair packed f16 writes).
// ---------------------------------------------------------------------------

// issue-only, non-rematerializable 16B load
__device__ __forceinline__ float4 gld(const float* p) {
  float4 r;
  asm volatile("global_load_dwordx4 %0, %1, off" : "=v"(r) : "v"(p));
  return r;
}

__device__ __forceinline__ void waitv0() {
  asm volatile("s_waitcnt vmcnt(0)" ::: "memory");
  __builtin_amdgcn_sched_barrier(0);
}

// raw barrier: drain LDS ops only
__device__ __forceinline__ void bar() {
  asm volatile("s_waitcnt lgkmcnt(0)\n\ts_barrier" ::: "memory");
}

__device__ __forceinline__ unsigned pkh(float x, float y) {
  h2_t p = {(_Float16)x, (_Float16)y};
  return __builtin_bit_cast(unsigned, p);
}

// expand 8 packed f16 (int4) -> 2 float4 via v_cvt_f32_f16 (full-rate VALU)
__device__ __forceinline__ void cvt8(int4 v, float4& lo, float4& hi) {
  h2_t p0 = __builtin_bit_cast(h2_t, (unsigned)v.x);
  h2_t p1 = __builtin_bit_cast(h2_t, (unsigned)v.y);
  h2_t p2 = __builtin_bit_cast(h2_t, (unsigned)v.z);
  h2_t p3 = __builtin_bit_cast(h2_t, (unsigned)v.w);
  lo = float4{(float)p0[0], (float)p0[1], (float)p1[0], (float)p1[1]};
  hi = float4{(float)p2[0], (float)p2[1], (float)p3[0], (float)p3[1]};
}

// 16-elem dot: 16 scalar v_fma_f32
__device__ __forceinline__ float dot16f(float4 w0, float4 w1, float4 w2,
                                        float4 w3, float4 h0, float4 h1,
                                        float4 h2, float4 h3, float acc) {
  acc = fmaf(w0.x, h0.x, acc);
  acc = fmaf(w0.y, h0.y, acc);
  acc = fmaf(w0.z, h0.z, acc);
  acc = fmaf(w0.w, h0.w, acc);
  acc = fmaf(w1.x, h1.x, acc);
  acc = fmaf(w1.y, h1.y, acc);
  acc = fmaf(w1.z, h1.z, acc);
  acc = fmaf(w1.w, h1.w, acc);
  acc = fmaf(w2.x, h2.x, acc);
  acc = fmaf(w2.y, h2.y, acc);
  acc = fmaf(w2.z, h2.z, acc);
  acc = fmaf(w2.w, h2.w, acc);
  acc = fmaf(w3.x, h3.x, acc);
  acc = fmaf(w3.y, h3.y, acc);
  acc = fmaf(w3.z, h3.z, acc);
  acc = fmaf(w3.w, h3.w, acc);
  return acc;
}

template <int CTRL>
__device__ __forceinline__ float dpp_add(float x) {
  return x + __builtin_bit_cast(
                 float, __builtin_amdgcn_mov_dpp(__builtin_bit_cast(int, x),
                                                 CTRL, 0xf, 0xf, true));
}

__device__ __forceinline__ float red8(float v) {
  v = dpp_add<0xB1>(v);    // quad_perm [1,0,3,2]  (+ lane^1)
  v = dpp_add<0x4E>(v);    // quad_perm [2,3,0,1]  (+ lane^2)
  v = dpp_add<0x141>(v);   // row_half_mirror      (+ other quad of 8-group)
  return v;
}

__device__ __forceinline__ float fast_tanh(float x) {
  float e = __expf(2.0f * x);
  return 1.0f - 2.0f / (e + 1.0f);
}

__global__ __launch_bounds__(512)
__attribute__((amdgpu_waves_per_eu(1, 2)))
void rnn_fused(
    const float* __restrict__ xp1,
    const float* __restrict__ W_hh1, const float* __restrict__ W_ih2,
    const float* __restrict__ W_hh2, const float* __restrict__ b_ih2,
    const float* __restrict__ b_hh2, const float* __restrict__ W_proj,
    const float* __restrict__ b_proj, const float* __restrict__ gamma,
    const float* __restrict__ beta, float* __restrict__ out) {
  __shared__ __align__(16) _Float16 h1s[2][H];
  __shared__ __align__(16) _Float16 h2s[2][H];
  const int t = threadIdx.x;
  const int b = blockIdx.x;
  const int l = t & 63;
  const int w = t >> 6;
  const int g = (l >> 3) & 7;
  const int q = l & 7;
  const int r0 = 16 * w + 2 * g;    // row pair r0 (even), r0+1
  const int r1 = r0 + 1;

  // --- weight loads: issue-only asm + one wait; stay f32 (24 float4s) ------
  const float* pA = &W_hh1[r0 * H + 16 * q];
  const float* pB = &W_hh1[r1 * H + 16 * q];
  const float* pC = &W_ih2[r0 * H + 16 * q];
  const float* pD = &W_ih2[r1 * H + 16 * q];
  const float* pE = &W_hh2[r0 * H + 16 * q];
  const float* pF = &W_hh2[r1 * H + 16 * q];
  float4 A0 = gld(pA), A1 = gld(pA + 4), A2 = gld(pA + 8), A3 = gld(pA + 12);
  float4 B0 = gld(pB), B1 = gld(pB + 4), B2 = gld(pB + 8), B3 = gld(pB + 12);
  float4 C0 = gld(pC), C1 = gld(pC + 4), C2 = gld(pC + 8), C3 = gld(pC + 12);
  float4 D0 = gld(pD), D1 = gld(pD + 4), D2 = gld(pD + 8), D3 = gld(pD + 12);
  float4 E0 = gld(pE), E1 = gld(pE + 4), E2 = gld(pE + 8), E3 = gld(pE + 12);
  float4 F0 = gld(pF), F1 = gld(pF + 4), F2 = gld(pF + 8), F3 = gld(pF + 12);
  waitv0();

  const float bias2_0 = b_ih2[r0] + b_hh2[r0];
  const float bias2_1 = b_ih2[r1] + b_hh2[r1];

  // h1[-1], h2[-1] live in buffer parity (-1)&1 == 1
  if (t < H) { h1s[1][t] = (_Float16)0.f; h2s[1][t] = (_Float16)0.f; }
  __syncthreads();

  const float* xpr = xp1 + (size_t)b * T_STEPS * H + r0;  // pair base

  // peel i = 0: h1[0] = tanh(xp[0]); no h2 yet
  if (q == 0) {
    float2 x0 = *(const float2*)&xpr[0];
    *(unsigned*)&h1s[0][r0] = pkh(fast_tanh(x0.x), fast_tanh(x0.y));
  }
  __syncthreads();

  // 2-deep prefetch: xc for current step, xn for next
  float2 xc = *(const float2*)&xpr[1 * H];   // xp[1]
  float2 xn = *(const float2*)&xpr[2 * H];   // xp[2]

#define STEP(I, PAR)                                                         \
  {                                                                          \
    const _Float16* h1p = h1s[(PAR) ^ 1];   /* h1[I-1] */                    \
    const _Float16* h2p = h2s[(PAR)];       /* h2[I-2] */                    \
    _Float16* h1w = h1s[(PAR)];             /* h1[I]   */                    \
    _Float16* h2w = h2s[(PAR) ^ 1];         /* h2[I-1] */                    \
    float2 xf = float2{0.f, 0.f};                                            \
    if ((I) + 2 < T_STEPS) xf = *(const float2*)&xpr[(size_t)((I) + 2) * H]; \
    int4 l1 = *(const int4*)&h1p[16 * q];                                    \
    int4 u1 = *(const int4*)&h1p[16 * q + 8];                                \
    int4 l2 = *(const int4*)&h2p[16 * q];                                    \
    int4 u2 = *(const int4*)&h2p[16 * q + 8];                                \
    float4 f1a, f1b, f1c, f1d, f2a, f2b, f2c, f2d;                           \
    cvt8(l1, f1a, f1b); cvt8(u1, f1c, f1d);                                  \
    cvt8(l2, f2a, f2b); cvt8(u2, f2c, f2d);                                  \
    float a0 = dot16f(A0, A1, A2, A3, f1a, f1b, f1c, f1d, 0.f);              \
    float a1 = dot16f(B0, B1, B2, B3, f1a, f1b, f1c, f1d, 0.f);              \
    float c0 = dot16f(E0, E1, E2, E3, f2a, f2b, f2c, f2d, 0.f);              \
    float c1 = dot16f(F0, F1, F2, F3, f2a, f2b, f2c, f2d, 0.f);              \
    float bb0 = dot16f(C0, C1, C2, C3, f1a, f1b, f1c, f1d, c0);              \
    float bb1 = dot16f(D0, D1, D2, D3, f1a, f1b, f1c, f1d, c1);              \
    a0 = red8(a0); a1 = red8(a1);                                            \
    bb0 = red8(bb0); bb1 = red8(bb1);                                        \
    if (q == 0) {                                                            \
      *(unsigned*)&h1w[r0] =                                                 \
          pkh(fast_tanh(xc.x + a0), fast_tanh(xc.y + a1));                   \
      *(unsigned*)&h2w[r0] =                                                 \
          pkh(fast_tanh(bias2_0 + bb0), fast_tanh(bias2_1 + bb1));           \
    }                                                                        \
    bar();                                                                   \
    xc = xn; xn = xf;                                                        \
  }

  STEP(1, 1)
#pragma unroll 1
  for (int i = 2; i < T_STEPS; i += 2) {
    STEP(i, 0)
    STEP(i + 1, 1)
  }
#undef STEP

  // peel i = T: h2[T-1] = tanh(bias2 + W_ih2.h1[T-1] + W_hh2.h2[T-2])
  {
    const _Float16* h1p = h1s[1];           // h1[T-1]
    const _Float16* h2p = h2s[0];           // h2[T-2]
    _Float16* h2w = h2s[1];                 // h2[T-1]
    int4 l1 = *(const int4*)&h1p[16 * q];
    int4 u1 = *(const int4*)&h1p[16 * q + 8];
    int4 l2 = *(const int4*)&h2p[16 * q];
    int4 u2 = *(const int4*)&h2p[16 * q + 8];
    float4 f1a, f1b, f1c, f1d, f2a, f2b, f2c, f2d;
    cvt8(l1, f1a, f1b); cvt8(u1, f1c, f1d);
    cvt8(l2, f2a, f2b); cvt8(u2, f2c, f2d);
    float c0 = dot16f(E0, E1, E2, E3, f2a, f2b, f2c, f2d, 0.f);
    float c1 = dot16f(F0, F1, F2, F3, f2a, f2b, f2c, f2d, 0.f);
    float bb0 = dot16f(C0, C1, C2, C3, f1a, f1b, f1c, f1d, c0);
    float bb1 = dot16f(D0, D1, D2, D3, f1a, f1b, f1c, f1d, c1);
    bb0 = red8(bb0); bb1 = red8(bb1);
    if (q == 0) {
      *(unsigned*)&h2w[r0] =
          pkh(fast_tanh(bias2_0 + bb0), fast_tanh(bias2_1 + bb1));
    }
    bar();
  }

  // projection + LayerNorm on h2s[1]; lanes 0..63 == wave 0 exactly
  if (t < PROJ) {
    const float* wp = W_proj + t * H;
    float z = b_proj[t];
#pragma unroll
    for (int i = 0; i < 32; ++i) {
      float4 wv = *(const float4*)&wp[4 * i];
      z = fmaf(wv.x, (float)h2s[1][4 * i + 0], z);
      z = fmaf(wv.y, (float)h2s[1][4 * i + 1], z);
      z = fmaf(wv.z, (float)h2s[1][4 * i + 2], z);
      z = fmaf(wv.w, (float)h2s[1][4 * i + 3], z);
    }
    float s = z;
#pragma unroll
    for (int d = 1; d < 64; d <<= 1) s += __shfl_xor(s, d);
    float mu = s * 0.015625f;
    float dz = z - mu;
    float v = dz * dz;
#pragma unroll
    for (int d = 1; d < 64; d <<= 1) v += __shfl_xor(v, d);
    float rstd = rsqrtf(v * 0.015625f + 1e-5f);
    out[b * PROJ + t] = dz * rstd * gamma[t] + beta[t];
  }
}

extern "C" void kernel_launch(void* const* d_in, const int* in_sizes, int n_in,
                              void* d_out, int out_size, void* d_ws, size_t ws_size,
                              hipStream_t stream) {
  const float* x      = (const float*)d_in[0];
  const float* W_ih1  = (const float*)d_in[1];
  const float* W_hh1  = (const float*)d_in[2];
  const float* b_ih1  = (const float*)d_in[3];
  const float* b_hh1  = (const float*)d_in[4];
  const float* W_ih2  = (const float*)d_in[5];
  const float* W_hh2  = (const float*)d_in[6];
  const float* b_ih2  = (const float*)d_in[7];
  const float* b_hh2  = (const float*)d_in[8];
  const float* W_proj = (const float*)d_in[9];
  const float* b_proj = (const float*)d_in[10];
  const float* gamma  = (const float*)d_in[11];
  const float* beta   = (const float*)d_in[12];

  float* xp1 = (float*)d_ws;   // BT*H*4 = 16 MB scratch

  xp1_gemm<<<BT / BM, 512, 0, stream>>>(x, W_ih1, b_ih1, b_hh1, xp1);
  rnn_fused<<<BATCH, 512, 0, stream>>>(xp1, W_hh1, W_ih2, W_hh2, b_ih2, b_hh2,
                                       W_proj, b_proj, gamma, beta,
                                       (float*)d_out);
}

// Round 16
// 397.226 us; speedup vs baseline: 1.2044x; 1.2044x over previous
//
#include <hip/hip_runtime.h>
#include <math.h>

#define H 128
#define IN 2048
#define PROJ 64
#define BT 32768      // B*T rows of x
#define T_STEPS 512
#define BATCH 64
#define BM 128
#define BKA 64

using f32x4  = __attribute__((ext_vector_type(4))) float;
using bfrag  = __attribute__((ext_vector_type(8))) short;   // 8 bf16
using h2_t   = __attribute__((ext_vector_type(2))) _Float16;

// v_cvt_pk_bf16_f32: d.lo = bf16(lo), d.hi = bf16(hi)  (RNE)
__device__ __forceinline__ unsigned cvtpk(float lo, float hi) {
  unsigned r;
  asm("v_cvt_pk_bf16_f32 %0, %1, %2" : "=v"(r) : "v"(lo), "v"(hi));
  return r;
}

// ---------------------------------------------------------------------------
// Kernel A: xp1[BT][H] = x[BT][IN] @ W_ih1^T + (b_ih1+b_hh1), bf16 MFMA.
// 256 blocks x 512 thr (8 waves, 2Mx4N). Tile 128(M) x 128(N=H) x 64(K).
// Reg-staged 1-deep pipeline, one barrier per chunk, XOR-swizzled LDS.
// ~60 us, near the 268 MB / 6.3 TB/s HBM floor.
// ---------------------------------------------------------------------------
__global__ __launch_bounds__(512) void xp1_gemm(
    const float* __restrict__ x, const float* __restrict__ W,
    const float* __restrict__ b1, const float* __restrict__ b2,
    float* __restrict__ xp1) {
  __shared__ __align__(16) char As[2][BM * BKA * 2];   // 2 x 16 KB
  __shared__ __align__(16) char Bs[2][H * BKA * 2];    // 2 x 16 KB
  const int t  = threadIdx.x;
  const int m0 = blockIdx.x * BM;
  const int wv = t >> 6, l = t & 63;
  const int wm = wv >> 2;
  const int wn = wv & 3;
  const int lr = l & 15;
  const int lq = l >> 4;

  const float* xg[4];
  const float* wg[4];
  int so[4];
#pragma unroll
  for (int i = 0; i < 4; ++i) {
    int c = t + 512 * i, r = c >> 4, k4 = c & 15;
    xg[i] = x + (size_t)(m0 + r) * IN + k4 * 4;
    wg[i] = W + (size_t)r * IN + k4 * 4;
    so[i] = (r * 128 + k4 * 8) ^ ((r & 7) << 4);
  }
  int ao[2][4], bo[2][2];
#pragma unroll
  for (int kf = 0; kf < 2; ++kf) {
#pragma unroll
    for (int mf = 0; mf < 4; ++mf) {
      int r = wm * 64 + mf * 16 + lr;
      ao[kf][mf] = (r * 128 + kf * 64 + lq * 16) ^ ((r & 7) << 4);
    }
#pragma unroll
    for (int nf = 0; nf < 2; ++nf) {
      int r = wn * 32 + nf * 16 + lr;
      bo[kf][nf] = (r * 128 + kf * 64 + lq * 16) ^ ((r & 7) << 4);
    }
  }

  f32x4 acc[4][2];
#pragma unroll
  for (int mf = 0; mf < 4; ++mf)
#pragma unroll
    for (int nf = 0; nf < 2; ++nf)
#pragma unroll
      for (int j = 0; j < 4; ++j) acc[mf][nf][j] = 0.f;

  float4 xr[4], wr[4];
#pragma unroll
  for (int i = 0; i < 4; ++i) {
    xr[i] = *(const float4*)&xg[i][0];
    wr[i] = *(const float4*)&wg[i][0];
  }
#pragma unroll
  for (int i = 0; i < 4; ++i) {
    uint2 ux; ux.x = cvtpk(xr[i].x, xr[i].y); ux.y = cvtpk(xr[i].z, xr[i].w);
    *(uint2*)(As[0] + so[i]) = ux;
    uint2 uw; uw.x = cvtpk(wr[i].x, wr[i].y); uw.y = cvtpk(wr[i].z, wr[i].w);
    *(uint2*)(Bs[0] + so[i]) = uw;
  }
  __syncthreads();

  for (int tc = 0; tc < 32; ++tc) {
    const int kc = (tc + 1) * BKA;
    if (tc < 31) {
#pragma unroll
      for (int i = 0; i < 4; ++i) {
        xr[i] = *(const float4*)&xg[i][kc];
        wr[i] = *(const float4*)&wg[i][kc];
      }
    }
    const char* Ab = As[tc & 1];
    const char* Bb = Bs[tc & 1];
#pragma unroll
    for (int kf = 0; kf < 2; ++kf) {
      bfrag af[4], bf[2];
#pragma unroll
      for (int mf = 0; mf < 4; ++mf) af[mf] = *(const bfrag*)(Ab + ao[kf][mf]);
#pragma unroll
      for (int nf = 0; nf < 2; ++nf) bf[nf] = *(const bfrag*)(Bb + bo[kf][nf]);
#pragma unroll
      for (int mf = 0; mf < 4; ++mf)
#pragma unroll
        for (int nf = 0; nf < 2; ++nf)
          acc[mf][nf] = __builtin_amdgcn_mfma_f32_16x16x32_bf16(
              af[mf], bf[nf], acc[mf][nf], 0, 0, 0);
    }
    if (tc < 31) {
      char* Aw = As[(tc + 1) & 1];
      char* Bw = Bs[(tc + 1) & 1];
#pragma unroll
      for (int i = 0; i < 4; ++i) {
        uint2 ux; ux.x = cvtpk(xr[i].x, xr[i].y); ux.y = cvtpk(xr[i].z, xr[i].w);
        *(uint2*)(Aw + so[i]) = ux;
        uint2 uw; uw.x = cvtpk(wr[i].x, wr[i].y); uw.y = cvtpk(wr[i].z, wr[i].w);
        *(uint2*)(Bw + so[i]) = uw;
      }
    }
    __syncthreads();
  }

  // epilogue: C/D layout col = lane&15, row = (lane>>4)*4 + j   [m89]
#pragma unroll
  for (int nf = 0; nf < 2; ++nf) {
    int n = wn * 32 + nf * 16 + lr;
    float bias = b1[n] + b2[n];
#pragma unroll
    for (int mf = 0; mf < 4; ++mf) {
      int mr = m0 + wm * 64 + mf * 16 + lq * 4;
#pragma unroll
      for (int j = 0; j < 4; ++j)
        xp1[(size_t)(mr + j) * H + n] = acc[mf][nf][j] + bias;
    }
  }
}

// ---------------------------------------------------------------------------
// Kernel B: fused 2-layer tanh RNN — best-measured configuration (R12):
// skewed single-phase (h1[i] & h2[i-1] per iter), 64 blocks x 512 thr,
// f16 dot2 datapath, asm-resident f16 weights (non-remat loads), raw
// lgkm-only barrier, parity-unrolled (compile-time buffer selects), 2-deep
// xp prefetch, row-pair packed ds_write_b32. 337 us, 0 bank conflicts.
// Residual ~1200 cyc/step is the dependent-chain latency of the serial
// recurrence (8 falsified structural theories; see session journal R6-R15).
// ---------------------------------------------------------------------------
struct Wrow { unsigned p0, p1, p2, p3, p4, p5, p6, p7; };  // 16 f16 = 8 h2

// issue-only, non-rematerializable 16B load
__device__ __forceinline__ float4 gld(const float* p) {
  float4 r;
  asm volatile("global_load_dwordx4 %0, %1, off" : "=v"(r) : "v"(p));
  return r;
}

__device__ __forceinline__ void waitv0() {
  asm volatile("s_waitcnt vmcnt(0)" ::: "memory");
  __builtin_amdgcn_sched_barrier(0);
}

// raw barrier: drain LDS ops only
__device__ __forceinline__ void bar() {
  asm volatile("s_waitcnt lgkmcnt(0)\n\ts_barrier" ::: "memory");
}

__device__ __forceinline__ unsigned pkh(float x, float y) {
  h2_t p = {(_Float16)x, (_Float16)y};
  return __builtin_bit_cast(unsigned, p);
}

__device__ __forceinline__ Wrow packrow(float4 a, float4 b, float4 c,
                                        float4 d) {
  Wrow w = {pkh(a.x, a.y), pkh(a.z, a.w), pkh(b.x, b.y), pkh(b.z, b.w),
            pkh(c.x, c.y), pkh(c.z, c.w), pkh(d.x, d.y), pkh(d.z, d.w)};
  return w;
}

__device__ __forceinline__ float d2(unsigned w, int h, float acc) {
  return __builtin_amdgcn_fdot2(__builtin_bit_cast(h2_t, w),
                                __builtin_bit_cast(h2_t, (unsigned)h), acc,
                                false);
}

__device__ __forceinline__ float dot16(Wrow w, int4 lo, int4 hi, float acc) {
  acc = d2(w.p0, lo.x, acc);
  acc = d2(w.p1, lo.y, acc);
  acc = d2(w.p2, lo.z, acc);
  acc = d2(w.p3, lo.w, acc);
  acc = d2(w.p4, hi.x, acc);
  acc = d2(w.p5, hi.y, acc);
  acc = d2(w.p6, hi.z, acc);
  acc = d2(w.p7, hi.w, acc);
  return acc;
}

template <int CTRL>
__device__ __forceinline__ float dpp_add(float x) {
  return x + __builtin_bit_cast(
                 float, __builtin_amdgcn_mov_dpp(__builtin_bit_cast(int, x),
                                                 CTRL, 0xf, 0xf, true));
}

__device__ __forceinline__ float red8(float v) {
  v = dpp_add<0xB1>(v);    // quad_perm [1,0,3,2]  (+ lane^1)
  v = dpp_add<0x4E>(v);    // quad_perm [2,3,0,1]  (+ lane^2)
  v = dpp_add<0x141>(v);   // row_half_mirror      (+ other quad of 8-group)
  return v;
}

__device__ __forceinline__ float fast_tanh(float x) {
  float e = __expf(2.0f * x);
  return 1.0f - 2.0f / (e + 1.0f);
}

__global__ __launch_bounds__(512)
__attribute__((amdgpu_waves_per_eu(1, 2)))
void rnn_fused(
    const float* __restrict__ xp1,
    const float* __restrict__ W_hh1, const float* __restrict__ W_ih2,
    const float* __restrict__ W_hh2, const float* __restrict__ b_ih2,
    const float* __restrict__ b_hh2, const float* __restrict__ W_proj,
    const float* __restrict__ b_proj, const float* __restrict__ gamma,
    const float* __restrict__ beta, float* __restrict__ out) {
  __shared__ __align__(16) _Float16 h1s[2][H];
  __shared__ __align__(16) _Float16 h2s[2][H];
  const int t = threadIdx.x;
  const int b = blockIdx.x;
  const int l = t & 63;
  const int w = t >> 6;
  const int g = (l >> 3) & 7;
  const int q = l & 7;
  const int r0 = 16 * w + 2 * g;    // row pair r0 (even), r0+1
  const int r1 = r0 + 1;

  // --- weight loads: issue-only asm + one wait (R6-proven residency) -------
  const float* pA = &W_hh1[r0 * H + 16 * q];
  const float* pB = &W_hh1[r1 * H + 16 * q];
  const float* pC = &W_ih2[r0 * H + 16 * q];
  const float* pD = &W_ih2[r1 * H + 16 * q];
  const float* pE = &W_hh2[r0 * H + 16 * q];
  const float* pF = &W_hh2[r1 * H + 16 * q];
  float4 A0 = gld(pA), A1 = gld(pA + 4), A2 = gld(pA + 8), A3 = gld(pA + 12);
  float4 B0 = gld(pB), B1 = gld(pB + 4), B2 = gld(pB + 8), B3 = gld(pB + 12);
  float4 C0 = gld(pC), C1 = gld(pC + 4), C2 = gld(pC + 8), C3 = gld(pC + 12);
  float4 D0 = gld(pD), D1 = gld(pD + 4), D2 = gld(pD + 8), D3 = gld(pD + 12);
  float4 E0 = gld(pE), E1 = gld(pE + 4), E2 = gld(pE + 8), E3 = gld(pE + 12);
  float4 F0 = gld(pF), F1 = gld(pF + 4), F2 = gld(pF + 8), F3 = gld(pF + 12);
  waitv0();

  Wrow W1r0 = packrow(A0, A1, A2, A3);
  Wrow W1r1 = packrow(B0, B1, B2, B3);
  Wrow W2r0 = packrow(C0, C1, C2, C3);
  Wrow W2r1 = packrow(D0, D1, D2, D3);
  Wrow W3r0 = packrow(E0, E1, E2, E3);
  Wrow W3r1 = packrow(F0, F1, F2, F3);

  const float bias2_0 = b_ih2[r0] + b_hh2[r0];
  const float bias2_1 = b_ih2[r1] + b_hh2[r1];

  // h1[-1], h2[-1] live in buffer parity (-1)&1 == 1
  if (t < H) { h1s[1][t] = (_Float16)0.f; h2s[1][t] = (_Float16)0.f; }
  __syncthreads();

  const float* xpr = xp1 + (size_t)b * T_STEPS * H + r0;  // pair base

  // peel i = 0: h1[0] = tanh(xp[0]); no h2 yet
  if (q == 0) {
    float2 x0 = *(const float2*)&xpr[0];
    *(unsigned*)&h1s[0][r0] = pkh(fast_tanh(x0.x), fast_tanh(x0.y));
  }
  __syncthreads();

  // 2-deep prefetch: xc for current step, xn for next
  float2 xc = *(const float2*)&xpr[1 * H];   // xp[1]
  float2 xn = *(const float2*)&xpr[2 * H];   // xp[2]

#define STEP(I, PAR)                                                         \
  {                                                                          \
    const _Float16* h1p = h1s[(PAR) ^ 1];   /* h1[I-1] */                    \
    const _Float16* h2p = h2s[(PAR)];       /* h2[I-2] */                    \
    _Float16* h1w = h1s[(PAR)];             /* h1[I]   */                    \
    _Float16* h2w = h2s[(PAR) ^ 1];         /* h2[I-1] */                    \
    float2 xf = float2{0.f, 0.f};                                            \
    if ((I) + 2 < T_STEPS) xf = *(const float2*)&xpr[(size_t)((I) + 2) * H]; \
    int4 l1 = *(const int4*)&h1p[16 * q];                                    \
    int4 u1 = *(const int4*)&h1p[16 * q + 8];                                \
    int4 l2 = *(const int4*)&h2p[16 * q];                                    \
    int4 u2 = *(const int4*)&h2p[16 * q + 8];                                \
    float a0 = dot16(W1r0, l1, u1, 0.f);                                     \
    float a1 = dot16(W1r1, l1, u1, 0.f);                                     \
    float c0 = dot16(W3r0, l2, u2, 0.f);                                     \
    float c1 = dot16(W3r1, l2, u2, 0.f);                                     \
    float bb0 = dot16(W2r0, l1, u1, c0);                                     \
    float bb1 = dot16(W2r1, l1, u1, c1);                                     \
    a0 = red8(a0); a1 = red8(a1);                                            \
    bb0 = red8(bb0); bb1 = red8(bb1);                                        \
    if (q == 0) {                                                            \
      *(unsigned*)&h1w[r0] =                                                 \
          pkh(fast_tanh(xc.x + a0), fast_tanh(xc.y + a1));                   \
      *(unsigned*)&h2w[r0] =                                                 \
          pkh(fast_tanh(bias2_0 + bb0), fast_tanh(bias2_1 + bb1));           \
    }                                                                        \
    bar();                                                                   \
    xc = xn; xn = xf;                                                        \
  }

  STEP(1, 1)
#pragma unroll 1
  for (int i = 2; i < T_STEPS; i += 2) {
    STEP(i, 0)
    STEP(i + 1, 1)
  }
#undef STEP

  // peel i = T: h2[T-1] = tanh(bias2 + W_ih2.h1[T-1] + W_hh2.h2[T-2])
  {
    const _Float16* h1p = h1s[1];           // h1[T-1]
    const _Float16* h2p = h2s[0];           // h2[T-2]
    _Float16* h2w = h2s[1];                 // h2[T-1]
    int4 l1 = *(const int4*)&h1p[16 * q];
    int4 u1 = *(const int4*)&h1p[16 * q + 8];
    int4 l2 = *(const int4*)&h2p[16 * q];
    int4 u2 = *(const int4*)&h2p[16 * q + 8];
    float c0 = dot16(W3r0, l2, u2, 0.f);
    float c1 = dot16(W3r1, l2, u2, 0.f);
    float bb0 = dot16(W2r0, l1, u1, c0);
    float bb1 = dot16(W2r1, l1, u1, c1);
    bb0 = red8(bb0); bb1 = red8(bb1);
    if (q == 0) {
      *(unsigned*)&h2w[r0] =
          pkh(fast_tanh(bias2_0 + bb0), fast_tanh(bias2_1 + bb1));
    }
    bar();
  }

  // projection + LayerNorm on h2s[1]; lanes 0..63 == wave 0 exactly
  if (t < PROJ) {
    const float* wp = W_proj + t * H;
    float z = b_proj[t];
#pragma unroll
    for (int i = 0; i < 32; ++i) {
      float4 wv = *(const float4*)&wp[4 * i];
      z = fmaf(wv.x, (float)h2s[1][4 * i + 0], z);
      z = fmaf(wv.y, (float)h2s[1][4 * i + 1], z);
      z = fmaf(wv.z, (float)h2s[1][4 * i + 2], z);
      z = fmaf(wv.w, (float)h2s[1][4 * i + 3], z);
    }
    float s = z;
#pragma unroll
    for (int d = 1; d < 64; d <<= 1) s += __shfl_xor(s, d);
    float mu = s * 0.015625f;
    float dz = z - mu;
    float v = dz * dz;
#pragma unroll
    for (int d = 1; d < 64; d <<= 1) v += __shfl_xor(v, d);
    float rstd = rsqrtf(v * 0.015625f + 1e-5f);
    out[b * PROJ + t] = dz * rstd * gamma[t] + beta[t];
  }
}

extern "C" void kernel_launch(void* const* d_in, const int* in_sizes, int n_in,
                              void* d_out, int out_size, void* d_ws, size_t ws_size,
                              hipStream_t stream) {
  const float* x      = (const float*)d_in[0];
  const float* W_ih1  = (const float*)d_in[1];
  const float* W_hh1  = (const float*)d_in[2];
  const float* b_ih1  = (const float*)d_in[3];
  const float* b_hh1  = (const float*)d_in[4];
  const float* W_ih2  = (const float*)d_in[5];
  const float* W_hh2  = (const float*)d_in[6];
  const float* b_ih2  = (const float*)d_in[7];
  const float* b_hh2  = (const float*)d_in[8];
  const float* W_proj = (const float*)d_in[9];
  const float* b_proj = (const float*)d_in[10];
  const float* gamma  = (const float*)d_in[11];
  const float* beta   = (const float*)d_in[12];

  float* xp1 = (float*)d_ws;   // BT*H*4 = 16 MB scratch

  xp1_gemm<<<BT / BM, 512, 0, stream>>>(x, W_ih1, b_ih1, b_hh1, xp1);
  rnn_fused<<<BATCH, 512, 0, stream>>>(xp1, W_hh1, W_ih2, W_hh2, b_ih2, b_hh2,
                                       W_proj, b_proj, gamma, beta,
                                       (float*)d_out);
}